// Round 1
// baseline (1041.887 us; speedup 1.0000x reference)
//
#include <hip/hip_runtime.h>
#include <math.h>

// KAN 1xN layer: out[o][n] = sum_p params[o][p] * basis[p](x[n])
// basis rows 0..126: degree-3 B-spline on knots
//   k[0..2]=0, k[3+i]=i/124 (i=0..124), k[128..130]=1
// basis row 127: silu(x)
// For x in [k_m, k_{m+1}), m = 3 + floor(x*124), only basis rows
// (m-3)..m are nonzero -> 5-term sparse dot per output element.

#define KAN_N_PARAMS 128
#define KAN_N_OUT    1024
#define KAN_N_X      262144
#define KAN_OT       64      // o-tile per block
#define KAN_BT       256     // threads per block

__device__ __forceinline__ float kan_knot(int i) {
    // k[i] = clamp(i-3, 0, 124) / 124
    int t = i - 3;
    t = t < 0 ? 0 : (t > 124 ? 124 : t);
    return (float)t * (1.0f / 124.0f);
}

__global__ __launch_bounds__(KAN_BT) void kan1xn_kernel(
    const float* __restrict__ X,      // (N_X)
    const float* __restrict__ P,      // (N_OUT, N_PARAMS)
    float* __restrict__ out)          // (N_OUT, N_X)
{
    __shared__ float Pl[KAN_OT][KAN_N_PARAMS];   // 32 KB

    const int tid = threadIdx.x;
    const int o0  = blockIdx.y * KAN_OT;

    // ---- stage params tile (64x128 fp32) coalesced as float4 ----
    {
        const float4* Pv = (const float4*)(P + (size_t)o0 * KAN_N_PARAMS);
        float4* Lv = (float4*)(&Pl[0][0]);
        #pragma unroll
        for (int i = 0; i < (KAN_OT * KAN_N_PARAMS / 4) / KAN_BT; ++i) {
            Lv[tid + i * KAN_BT] = Pv[tid + i * KAN_BT];
        }
    }
    __syncthreads();

    // ---- per-thread sample: interval + de Boor basis (4 nonzero) ----
    const int n = blockIdx.x * KAN_BT + tid;
    const float x = X[n];

    int t = (int)(x * 124.0f);
    t = t < 0 ? 0 : (t > 123 ? 123 : t);
    const int m = t + 3;          // knot interval index: k[m] <= x < k[m+1]

    // de Boor basis-functions algorithm (NURBS book A2.2), degree 3.
    // After loop: Nb[r] = B_{m-3+r,3}(x), r=0..3.
    float Nb0 = 1.0f, Nb1 = 0.0f, Nb2 = 0.0f, Nb3 = 0.0f;
    float left[4], right[4];
    {
        // d = 1
        left[1]  = x - kan_knot(m);
        right[1] = kan_knot(m + 1) - x;
        float temp = Nb0 / (right[1] + left[1]);
        Nb0 = right[1] * temp;
        Nb1 = left[1] * temp;
        // d = 2
        left[2]  = x - kan_knot(m - 1);
        right[2] = kan_knot(m + 2) - x;
        float saved = 0.0f;
        temp = Nb0 / (right[1] + left[2]);
        Nb0 = saved + right[1] * temp;
        saved = left[2] * temp;
        temp = Nb1 / (right[2] + left[1]);
        Nb1 = saved + right[2] * temp;
        Nb2 = left[1] * temp;
        // d = 3
        left[3]  = x - kan_knot(m - 2);
        right[3] = kan_knot(m + 3) - x;
        saved = 0.0f;
        temp = Nb0 / (right[1] + left[3]);
        Nb0 = saved + right[1] * temp;
        saved = left[3] * temp;
        temp = Nb1 / (right[2] + left[2]);
        Nb1 = saved + right[2] * temp;
        saved = left[2] * temp;
        temp = Nb2 / (right[3] + left[1]);
        Nb2 = saved + right[3] * temp;
        Nb3 = left[1] * temp;
    }
    const float s = x / (1.0f + __expf(-x));   // silu(x), row 127
    const int b = t;                            // first nonzero basis row

    // ---- o-loop: 5-term sparse dot per output, coalesced stores ----
    float* outp = out + (size_t)o0 * KAN_N_X + n;
    #pragma unroll 4
    for (int o = 0; o < KAN_OT; ++o) {
        const float* row = &Pl[o][0];
        float v = Nb0 * row[b]
                + Nb1 * row[b + 1]
                + Nb2 * row[b + 2]
                + Nb3 * row[b + 3]
                + s   * row[127];
        outp[(size_t)o * KAN_N_X] = v;
    }
}

extern "C" void kernel_launch(void* const* d_in, const int* in_sizes, int n_in,
                              void* d_out, int out_size, void* d_ws, size_t ws_size,
                              hipStream_t stream) {
    const float* X = (const float*)d_in[0];   // (262144) fp32
    const float* P = (const float*)d_in[1];   // (1024, 128) fp32
    float* out = (float*)d_out;               // (1024, 262144) fp32

    dim3 grid(KAN_N_X / KAN_BT, KAN_N_OUT / KAN_OT);  // (1024, 16)
    dim3 block(KAN_BT);
    hipLaunchKernelGGL(kan1xn_kernel, grid, block, 0, stream, X, P, out);
}